// Round 8
// baseline (37.930 us; speedup 1.0000x reference)
//
#include <hip/hip_runtime.h>
#include <hip/hip_bf16.h>

#define N 4096
#define FIN 128
#define U0 16
#define H0 4
#define MAXD 128        // padded neighbor-list cap; P(deg>128), Binom(4096,0.01) ~ 0
#define NGEMM (N / 16)  // 256 gemm blocks

// ---------------------------------------------------------------------------
// K1 fused: blocks [0,256): h0 = x@w0, a1/a2 = h0@aw, partS0 plain stores
//           blocks [256, 256+N): adj row -> padded CSR via LDS compaction
// No atomics, no preceding memset node.
// ---------------------------------------------------------------------------
__global__ void k1_fused(const float* __restrict__ adj, const float* __restrict__ x,
                         const float* __restrict__ w0, const float* __restrict__ aw1,
                         const float* __restrict__ aw2,
                         int* __restrict__ deg, int* __restrict__ cols,
                         float* __restrict__ h0, float* __restrict__ a1,
                         float* __restrict__ a2, float* __restrict__ partS0) {
    const int t = threadIdx.x;
    if (blockIdx.x < NGEMM) {
        // ---------------- gemm0 ----------------
        const int bid = blockIdx.x;
        __shared__ float xs[16][FIN + 1];
        __shared__ float ws[FIN][U0];
        __shared__ float hs[16][U0 + 1];
        const int r0 = bid * 16;

        for (int k = t; k < FIN * U0; k += 256) ws[k / U0][k % U0] = w0[k];
        for (int k = t; k < 16 * FIN; k += 256)
            xs[k / FIN][k % FIN] = x[(size_t)(r0 + k / FIN) * FIN + (k % FIN)];
        __syncthreads();

        const int r = t / U0, u = t % U0;
        float acc = 0.f;
        #pragma unroll 8
        for (int k = 0; k < FIN; ++k) acc += xs[r][k] * ws[k][u];
        hs[r][u] = acc;
        h0[(size_t)(r0 + r) * U0 + u] = acc;
        __syncthreads();

        if (t < 16 * H0) {                 // 64 threads: (row, head)
            const int rr = t / H0, hh = t % H0;
            float s1 = 0.f, s2 = 0.f;
            #pragma unroll
            for (int u2 = 0; u2 < U0; ++u2) {
                float hv = hs[rr][u2];
                s1 += hv * aw1[u2 * H0 + hh];
                s2 += hv * aw2[u2 * H0 + hh];
            }
            a1[(r0 + rr) * H0 + hh] = s1;
            a2[(r0 + rr) * H0 + hh] = s2;
        } else if (t >= 128 && t < 144) {  // 16 threads: column partial, plain store
            const int d = t - 128;
            float s = 0.f;
            #pragma unroll
            for (int rr = 0; rr < 16; ++rr) s += hs[rr][d];
            partS0[bid * 16 + d] = s;
        }
    } else {
        // ---------------- CSR build ----------------
        const int row = blockIdx.x - NGEMM;
        const int lane = t & 63, wid = t >> 6;
        const float4* __restrict__ arow =
            reinterpret_cast<const float4*>(adj + (size_t)row * N);

        __shared__ int cls[MAXD];
        __shared__ int wsum[4];
        __shared__ int dgs;

        float4 v[4];
        int c = 0;
        #pragma unroll
        for (int p = 0; p < 4; ++p) {
            v[p] = arow[t + 256 * p];
            c += (v[p].x != 0.f) + (v[p].y != 0.f) + (v[p].z != 0.f) + (v[p].w != 0.f);
        }

        int sc = c;                          // inclusive wave scan (6 shfl steps)
        #pragma unroll
        for (int s = 1; s < 64; s <<= 1) {
            int u = __shfl_up(sc, s);
            if (lane >= s) sc += u;
        }
        if (lane == 63) wsum[wid] = sc;
        __syncthreads();
        int base = 0;
        #pragma unroll
        for (int w2 = 0; w2 < 4; ++w2)
            if (w2 < wid) base += wsum[w2];
        const int off = base + sc - c;
        if (t == 255) {
            const int dgv = min(base + sc, MAXD);
            dgs = dgv;
            deg[row] = dgv;
        }

        int w = off;                          // compact into LDS
        #pragma unroll
        for (int p = 0; p < 4; ++p) {
            const int j0 = (t + 256 * p) * 4;
            if (v[p].x != 0.f && w < MAXD) cls[w++] = j0;
            if (v[p].y != 0.f && w < MAXD) cls[w++] = j0 + 1;
            if (v[p].z != 0.f && w < MAXD) cls[w++] = j0 + 2;
            if (v[p].w != 0.f && w < MAXD) cls[w++] = j0 + 3;
        }
        __syncthreads();
        if (t < dgs) cols[(size_t)row * MAXD + t] = cls[t];  // coalesced store
    }
}

// ---------------------------------------------------------------------------
// K2: layer-0 sparse attention + relu + hp = h1@w1.  One block per row;
// per-block partS0 reduce (L2-hot); 4 waves stride the LDS neighbor list;
// gather hand-unrolled x4 (8 independent L2 loads in flight). No atomics.
// ---------------------------------------------------------------------------
__global__ void attn0(const float* __restrict__ h0, const float* __restrict__ a1,
                      const float* __restrict__ a2, const float* __restrict__ partS0,
                      const int* __restrict__ deg, const int* __restrict__ cols,
                      const float* __restrict__ w1, float* __restrict__ hp) {
    const int i = blockIdx.x;
    const int t = threadIdx.x;
    __shared__ int cls[MAXD];
    __shared__ float red[16][17];
    __shared__ float s0s[16];
    __shared__ float ln[4][64];
    __shared__ float ld[4][64];

    const int dg = deg[i];
    if (t < MAXD) cls[t] = (t < dg) ? cols[(size_t)i * MAXD + t] : 0;  // pad -> row 0

    // partS0 [256][16] -> s0s[16] (16 coalesced strided reads/thread)
    {
        const int d = t & 15, ch = t >> 4;
        float s = 0.f;
        #pragma unroll
        for (int k = ch; k < 256; k += 16) s += partS0[k * 16 + d];
        red[ch][d] = s;
    }
    __syncthreads();
    if (t < 16) {
        float s2 = 0.f;
        #pragma unroll
        for (int k = 0; k < 16; ++k) s2 += red[k][t];
        s0s[t] = s2;
    }
    __syncthreads();

    const int wid = t >> 6, lane = t & 63;
    const int hh = lane >> 4, d = lane & 15;
    const float a1v = a1[i * H0 + hh];

    float accn = 0.f, accd = 0.f;
    for (int c = 0; ; ++c) {
        const int kb = wid + 16 * c;           // this wave's next chunk base
        if (kb >= dg) break;                   // wave-uniform exit
        int ja[4];
        float ms[4];
        #pragma unroll
        for (int q = 0; q < 4; ++q) {
            const int k = kb + 4 * q;
            ja[q] = cls[k < MAXD ? k : 0];     // padded/clamped: always valid
            ms[q] = (k < dg) ? 1.f : 0.f;
        }
        float a2v[4], h0v[4];
        #pragma unroll
        for (int q = 0; q < 4; ++q) {          // 8 loads issued back-to-back
            a2v[q] = a2[ja[q] * H0 + hh];
            h0v[q] = h0[(size_t)ja[q] * U0 + d];
        }
        #pragma unroll
        for (int q = 0; q < 4; ++q) {
            float cc = a1v + a2v[q];
            cc = cc > 0.f ? cc : 0.f;
            const float e = (__expf(cc) - 1.f) * ms[q];
            accn = fmaf(e, h0v[q], accn);
            accd += e;
        }
    }
    ln[wid][lane] = accn;
    ld[wid][lane] = accd;
    __syncthreads();

    if (t < 64) {
        const float an = ln[0][t] + ln[1][t] + ln[2][t] + ln[3][t];
        const float ad = ld[0][t] + ld[1][t] + ld[2][t] + ld[3][t];
        float o = (an + s0s[t & 15]) / (ad + (float)N);
        o = o > 0.f ? o : 0.f;                 // relu -> h1[i, t]

        float pv = o * w1[t];                  // hp[i] = h1[i,:].w1
        #pragma unroll
        for (int off = 32; off; off >>= 1) pv += __shfl_down(pv, off);
        if (t == 0) hp[i] = pv;
    }
}

// ---------------------------------------------------------------------------
// K3: layer-1 sparse attention (scalar feature) + sigmoid -> out [4096].
// Stages all of hp (16 KB) into LDS (coalesced); S1 is a free block-reduce
// of the staged values; gather hits LDS. 4 rows/block, one wave per row.
// ---------------------------------------------------------------------------
__global__ void attn1(const float* __restrict__ hp,
                      const float* __restrict__ aw11, const float* __restrict__ aw21,
                      const int* __restrict__ deg, const int* __restrict__ cols,
                      float* __restrict__ out) {
    __shared__ float hps[N];          // 16 KB
    __shared__ int cls[4][MAXD];      // 2 KB
    __shared__ float s1red[4];
    const int t = threadIdx.x;
    const int w = t >> 6, lane = t & 63;
    const int i0 = blockIdx.x * 4;

    float s = 0.f;
    const float4* __restrict__ hp4 = reinterpret_cast<const float4*>(hp);
    #pragma unroll
    for (int k = t; k < N / 4; k += 256) {
        float4 v = hp4[k];
        reinterpret_cast<float4*>(hps)[k] = v;
        s += v.x + v.y + v.z + v.w;
    }
    for (int k = t; k < 4 * MAXD; k += 256)
        cls[k >> 7][k & 127] = cols[(size_t)(i0 + (k >> 7)) * MAXD + (k & 127)];

    #pragma unroll
    for (int o = 32; o; o >>= 1) s += __shfl_down(s, o);
    if (lane == 0) s1red[w] = s;
    __syncthreads();
    const float S1 = s1red[0] + s1red[1] + s1red[2] + s1red[3];

    const int i = i0 + w;
    const float w1v = aw11[0], w2v = aw21[0];
    const float a1v = hps[i] * w1v;
    const int dg = deg[i];

    float accn = 0.f, accd = 0.f;
    for (int k = lane; k < dg; k += 64) {
        const int j = cls[w][k];
        const float hj = hps[j];
        float cc = a1v + hj * w2v;
        cc = cc > 0.f ? cc : 0.f;
        const float e = __expf(cc) - 1.f;
        accn = fmaf(e, hj, accn);
        accd += e;
    }
    #pragma unroll
    for (int o = 32; o; o >>= 1) {
        accn += __shfl_down(accn, o);
        accd += __shfl_down(accd, o);
    }
    if (lane == 0) {
        const float v = (accn + S1) / (accd + (float)N);
        out[i] = 1.f / (1.f + __expf(-v));
    }
}

// ---------------------------------------------------------------------------
extern "C" void kernel_launch(void* const* d_in, const int* in_sizes, int n_in,
                              void* d_out, int out_size, void* d_ws, size_t ws_size,
                              hipStream_t stream) {
    const float* x    = (const float*)d_in[0];
    const float* adj  = (const float*)d_in[1];
    const float* w0   = (const float*)d_in[2];
    const float* aw10 = (const float*)d_in[3];
    const float* aw20 = (const float*)d_in[4];
    const float* w1   = (const float*)d_in[5];
    const float* aw11 = (const float*)d_in[6];
    const float* aw21 = (const float*)d_in[7];
    float* out = (float*)d_out;

    char* p = (char*)d_ws;
    auto alloc = [&](size_t bytes) {
        char* r = p;
        p += (bytes + 255) & ~(size_t)255;
        return r;
    };
    float* partS0 = (float*)alloc(NGEMM * 16 * 4);   // 16 KB
    float* h0     = (float*)alloc((size_t)N * U0 * 4);
    float* a1     = (float*)alloc((size_t)N * H0 * 4);
    float* a2     = (float*)alloc((size_t)N * H0 * 4);
    float* hp     = (float*)alloc((size_t)N * 4);
    int*   deg    = (int*)alloc((size_t)N * 4);
    int*   cols   = (int*)alloc((size_t)N * MAXD * 4);

    k1_fused<<<N + NGEMM, 256, 0, stream>>>(adj, x, w0, aw10, aw20,
                                            deg, cols, h0, a1, a2, partS0);
    attn0<<<N, 256, 0, stream>>>(h0, a1, a2, partS0, deg, cols, w1, hp);
    attn1<<<N / 4, 256, 0, stream>>>(hp, aw11, aw21, deg, cols, out);
}